// Round 9
// baseline (179.225 us; speedup 1.0000x reference)
//
#include <hip/hip_runtime.h>
#include <math.h>

// IDMForwardSim R14b (resubmit; round-8 bench was an infra container failure
// with no kernel verdict — same signature as the R11 flake which passed on
// resubmit). R13 + s_setprio(1) around the MFMA cluster (T5).
// Theory: R9-vs-R8/R13 shows the wall tracks per-CU work while pipes sum to
// only ~57% busy — the remaining ~40% is phase-convoy (a block's 7 waves
// sweep LDS->MFMA->trans in lockstep; nothing pushes the two co-resident
// blocks anti-phase). setprio favors MFMA-phase waves so the sibling block's
// gate-phase waves fill the VALU pipe underneath.
// Rider: sdv top-up moved from wave 0 (busiest: gates+tail) to wave 1.
// Otherwise R13: NB=16, 448 thr, 2 blocks/CU; tail-in-loop lag-2 wave 0 with
// 3-reg state (params in LDS pS, att_b folded into bp[100]); exp2 constants
// pre-folded into weights; fused-reciprocal gates.

#define B_TOT 8192
#define T_STEPS 40
#define NB 16

typedef _Float16 f16;
typedef f16 f16x8 __attribute__((ext_vector_type(8)));
typedef float f32x4 __attribute__((ext_vector_type(4)));

__device__ __forceinline__ float rcpf(float x) { return __builtin_amdgcn_rcpf(x); }
__device__ __forceinline__ float ex2(float x)  { return __builtin_amdgcn_exp2f(x); }
__device__ __forceinline__ float sigf(float x)  { return rcpf(1.f + ex2(-1.44269504f * x)); }

// ws layout (bytes): whb f16[65536] @0 | wxb f16[65536] @131072 | bp f32[512] @262144

__global__ __launch_bounds__(256) void idm_prep(
    const float* __restrict__ Wx, const float* __restrict__ Wh,
    const float* __restrict__ bvec, const float* __restrict__ attw,
    const float* __restrict__ attB,
    f16* __restrict__ whb, f16* __restrict__ wxb,
    float* __restrict__ bp)
{
  int i = blockIdx.x * 256 + threadIdx.x;  // 0..65535, i = k*512 + n (coalesced reads)
  int k = i >> 9, n = i & 511;
  int g = n >> 7, j128 = n & 127;
  // pre-scale: sigmoid gates (zi,zf,zo) by log2(e), tanh gate (zg) by 2*log2(e)
  float sc = (g == 2) ? 2.88539008f : 1.44269504f;
  float vh = 0.f, vx = 0.f;
  if (j128 < 100) {
    int col = g * 100 + j128;
    if (k < 100)      { vh = Wh[k * 400 + col] * sc; vx = Wx[k * 400 + col] * sc; }
    else if (k < 102) { vh = Wx[k * 400 + col] * sc; }  // sdv rows folded into Wh-pad
  } else if (n == 100 && k < 100) {
    vh = attw[k];  // logit column stays UNSCALED (z[n=100] = h . att_W)
  }
  // dest B-frag index: tile=n>>4, kf=k>>5, l=((k>>3)&3)*16+(n&15), j=k&7
  int idx = (((n >> 4) * 4 + (k >> 5)) * 64 + (((k >> 3) & 3) * 16 + (n & 15))) * 8 + (k & 7);
  whb[idx] = (f16)vh;
  wxb[idx] = (f16)vx;
  if (i < 512) {
    int gg = i >> 7, jj = i & 127;
    float scb = (gg == 2) ? 2.88539008f : 1.44269504f;
    // bp[100] carries att_b (logit column bias); other pad cols stay 0
    bp[i] = (jj < 100) ? bvec[gg * 100 + jj] * scb
                       : ((i == 100) ? attB[0] : 0.f);
  }
}

#define MM(z, a, g, kf) z = __builtin_amdgcn_mfma_f32_16x16x32_f16(a, wb[g][kf], z, 0, 0, 0)

// tail step (wave 0, lanes 0..15). Per-batch params read from LDS pS each
// step; only ego_v/ego_x/actT live across the t-loop.
#define TAIL_STEP(tt) {                                                        \
    int tt_ = (tt);                                                            \
    float inv_dv = pS[0][l], des_tg = pS[1][l], min_jx = pS[2][l];             \
    float max_a = pS[3][l], inv2s = pS[4][l];                                  \
    float2 s01 = *(const float2*)&sS[l][tt_][0];                               \
    float2 s23 = *(const float2*)&sS[l][tt_][2];                               \
    float2 s45 = *(const float2*)&sS[l][tt_][4];                               \
    float nf = nS[0][tt_][l], nm = nS[1][tt_][l];                              \
    float lg = logitS[tt_][l];                                                 \
    ego_v += actT * 0.1f;                                                      \
    ego_x += ego_v * 0.1f + actT * 0.005f;                                     \
    float dxf = fminf(fmaxf(s23.x - ego_x, 0.5f), 1000.f);                     \
    float dgf = min_jx + fmaxf(0.f, des_tg * ego_v + ego_v * (ego_v - s01.x) * inv2s); \
    float rr = ego_v * inv_dv; float rr2 = rr * rr;                            \
    float qf = dgf * rcpf(dxf);                                                \
    float af_ = fminf(fmaxf(max_a * (1.f - rr2 * rr2 - qf * qf), -3.f), 3.f);  \
    float dxm = fminf(fmaxf(s23.y - ego_x, 0.5f), 1000.f);                     \
    float dgm = min_jx + fmaxf(0.f, des_tg * ego_v + ego_v * (ego_v - s01.y) * inv2s); \
    float qm = dgm * rcpf(dxm);                                                \
    float am_ = fminf(fmaxf(max_a * (1.f - rr2 * rr2 - qm * qm), -3.f), 3.f);  \
    float ef2 = s45.x * af_ + (1.f - s45.x) * nf;                              \
    float em2 = s45.y * am_ + (1.f - s45.y) * nm;                              \
    float att = sigf(5.f * lg);                                                \
    actT = (1.f - att) * ef2 + att * em2;                                      \
    accS[0][l][tt_] = actT;                                                    \
    accS[1][l][tt_] = att;                                                     \
  }

__global__ __launch_bounds__(448, 4) void idm_main(
    const float* __restrict__ z_att,
    const float* __restrict__ linear_W,
    const float* __restrict__ linear_b,
    const float* __restrict__ sdv_acts,
    const f16* __restrict__ whb, const f16* __restrict__ wxb,
    const float* __restrict__ bp,
    const float* __restrict__ idm_params,
    const float* __restrict__ idm_s,
    const float* __restrict__ noise_f,
    const float* __restrict__ noise_m,
    float* __restrict__ out)
{
  __shared__ f16   hS[2][16][136];       // [buf][batch][k] 0..99 h, 100..101 sdv, pad 0
  __shared__ f16   sdvS[T_STEPS][16][2];
  __shared__ float logitS[T_STEPS][16];
  __shared__ float sS[16][T_STEPS][6];   // idm_s fields 1,2,4,5,6,7
  __shared__ float nS[2][T_STEPS][16];   // noise_f / noise_m
  __shared__ float accS[2][16][T_STEPS]; // act, att
  __shared__ float pS[5][16];            // inv_dv, des_tg, min_jx, max_a, inv2s

  const int tid = threadIdx.x;
  const int w  = tid >> 6;   // 0..6 j-tile
  const int l  = tid & 63;
  const int lr = l & 15;
  const int lq = l >> 4;
  const int b0g = blockIdx.x * NB;
  const int jcol = 16 * w + lr;
  const bool tail_lane = (tid < NB);  // wave 0, lanes 0..15

  // zero hS (pad rows must stay exact 0)
  for (int idx = tid; idx < 2176; idx += 448) ((unsigned*)hS)[idx] = 0u;
  // coalesced staging: sdv (1280 f), idm_s fields (5120 f), noise (1280 f)
  for (int idx = tid; idx < 1280; idx += 448) {
    float v = sdv_acts[(size_t)b0g * 80 + idx];
    int b = idx / 80, r = idx - b * 80;
    sdvS[r >> 1][b][r & 1] = (f16)v;
  }
  for (int idx = tid; idx < 5120; idx += 448) {
    int f = idx & 7;
    if (f != 0 && f != 3) {
      int b = idx / 320, rem = idx - b * 320, t = rem >> 3;
      sS[b][t][(f < 3) ? f - 1 : f - 2] = idm_s[(size_t)b0g * 320 + idx];
    }
  }
  for (int idx = tid; idx < 1280; idx += 448) {
    int which = idx >= 640 ? 1 : 0;
    int r = idx - which * 640;
    int t = r >> 4, i = r & 15;
    nS[which][t][i] = which ? noise_m[(size_t)t * B_TOT + b0g + i]
                            : noise_f[(size_t)t * B_TOT + b0g + i];
  }
  // params: 80 consecutive floats, coalesced; pS[j][b] = idm_params[(b0g+b)*5+j]
  if (tid < 80) pS[tid % 5][tid / 5] = idm_params[(size_t)b0g * 5 + tid];
  __syncthreads();

  // in-place transform: pS[0] -> 1/des_v, pS[4] -> 0.5/sqrt(max_a*min_a)
  if (tid < 16) {
    pS[0][tid] = rcpf(pS[0][tid]);
    pS[4][tid] = 0.5f / sqrtf(pS[3][tid] * pS[4][tid]);
  }

  // h0 = att_proj into hS[0]
  if (tid >= 64 && tid < 320) {
    int s2 = tid - 64;
    int b = s2 >> 4, oct = s2 & 15;
    float za[10];
    #pragma unroll
    for (int t2 = 0; t2 < 10; ++t2) za[t2] = z_att[(b0g + b) * 10 + t2];
    #pragma unroll
    for (int jj = 0; jj < 8; ++jj) {
      int j = oct * 8 + jj;
      if (j < 100) {
        float acc = linear_b[j];
        #pragma unroll
        for (int t2 = 0; t2 < 10; ++t2) acc = fmaf(za[t2], linear_W[t2 * 100 + j], acc);
        hS[0][b][j] = (f16)acc;
      }
    }
  }
  if (tid < 32) hS[0][tid >> 1][100 + (tid & 1)] = sdvS[0][tid >> 1][tid & 1];
  __syncthreads();

  // Wx frags -> cx, then Wh frags (loop-invariant in regs)
  f16x8 wb[4][4];
  #pragma unroll
  for (int g = 0; g < 4; ++g) {
    int tile = w + 8 * g;
    #pragma unroll
    for (int kf = 0; kf < 4; ++kf)
      wb[g][kf] = *(const f16x8*)(wxb + ((size_t)(tile * 4 + kf) * 64 + l) * 8);
  }
  f32x4 cx[4];
  #pragma unroll
  for (int g = 0; g < 4; ++g) {
    float bpv = bp[(w + 8 * g) * 16 + lr];
    f32x4 c = {bpv, bpv, bpv, bpv};
    cx[g] = c;
  }
  #pragma unroll
  for (int kf = 0; kf < 4; ++kf) {
    f16x8 a = *(const f16x8*)(&hS[0][lr][kf * 32 + lq * 8]);
    #pragma unroll
    for (int g = 0; g < 4; ++g)
      cx[g] = __builtin_amdgcn_mfma_f32_16x16x32_f16(a, wb[g][kf], cx[g], 0, 0, 0);
  }
  #pragma unroll
  for (int g = 0; g < 4; ++g) {
    int tile = w + 8 * g;
    #pragma unroll
    for (int kf = 0; kf < 4; ++kf)
      wb[g][kf] = *(const f16x8*)(whb + ((size_t)(tile * 4 + kf) * 64 + l) * 8);
  }

  float cst[4];
  #pragma unroll
  for (int r = 0; r < 4; ++r) cst[r] = (float)hS[0][lq * 4 + r][jcol];

  // tail recurrent state: the ONLY tail registers live across the t-loop
  float ego_v = 0.f, ego_x = 0.f, actT = 0.f;
  if (tail_lane) {
    ego_v = idm_s[(size_t)(b0g + l) * 320 + 0];
    ego_x = idm_s[(size_t)(b0g + l) * 320 + 3];
  }

  int p = 0;
  for (int t = 0; t < T_STEPS; ++t) {
    // A-frags for [h^{(t)}, sdv_t]
    f16x8 a0 = *(const f16x8*)(&hS[p][lr][0  + lq * 8]);
    f16x8 a1 = *(const f16x8*)(&hS[p][lr][32 + lq * 8]);
    f16x8 a2 = *(const f16x8*)(&hS[p][lr][64 + lq * 8]);
    f16x8 a3 = *(const f16x8*)(&hS[p][lr][96 + lq * 8]);
    f32x4 z0 = cx[0], z1 = cx[1], z2 = cx[2], z3 = cx[3];
    // T5: favor MFMA-phase waves; sibling block's gate-phase waves fill VALU.
    __builtin_amdgcn_s_setprio(1);
    MM(z0,a0,0,0); MM(z1,a0,1,0); MM(z2,a0,2,0); MM(z3,a0,3,0);
    MM(z0,a1,0,1); MM(z1,a1,1,1); MM(z2,a1,2,1); MM(z3,a1,3,1);
    MM(z0,a2,0,2); MM(z1,a2,1,2); MM(z2,a2,2,2); MM(z3,a2,3,2);
    MM(z0,a3,0,3); MM(z1,a3,1,3); MM(z2,a3,2,3); MM(z3,a3,3,3);
    __builtin_amdgcn_s_setprio(0);

    // logit for output t-1: z col n=100 (tile 6 = wave 6 g=0, lane lr==4);
    // includes att_b via bp[100] folded into cx
    if (w == 6 && t > 0 && lr == 4) {
      #pragma unroll
      for (int r = 0; r < 4; ++r) logitS[t - 1][lq * 4 + r] = z0[r];
    }

    // gates with fused reciprocals: si*tg = (e2-1)/((1+e0)(1+e2)),
    // so*tanh(cc) = (d-1)/((1+e3)(1+d)); e2,d clamped so overflow -> 0, no NaN.
    #pragma unroll
    for (int r = 0; r < 4; ++r) {
      float e0 = ex2(-z0[r]);
      float e1 = ex2(-z1[r]);
      float e2 = fminf(ex2(z2[r]), 1e30f);
      float e3 = ex2(-z3[r]);
      float sf  = rcpf(1.f + e1);
      float itg = (e2 - 1.f) * rcpf((1.f + e0) * (1.f + e2));  // si*tg
      float cc  = fmaf(sf, cst[r], itg);
      float d   = fminf(ex2(2.88539008f * cc), 1e30f);
      float hh  = (d - 1.f) * rcpf((1.f + e3) * (1.f + d));    // so*tanh(cc)
      cst[r] = cc;
      if (jcol < 100) hS[p ^ 1][lq * 4 + r][jcol] = (f16)hh;
    }
    // sdv top-up on wave 1 (wave 0 is the busiest: gates + tail chain)
    if (t + 1 < T_STEPS && tid >= 64 && tid < 96) {
      int ll = tid - 64;
      hS[p ^ 1][ll >> 1][100 + (ll & 1)] = sdvS[t + 1][ll >> 1][ll & 1];
    }
    // wave 0 lanes 0..15: lag-2 tail step (logit[t-2] visible since end of
    // step t-1); independent of this wave's gates, scheduler interleaves
    if (tail_lane && t >= 2) TAIL_STEP(t - 2);
    __syncthreads();  // single barrier per step
    p ^= 1;
  }

  // final logit (t = T-1) from h^{(T)} in hS[p]: 4 MFMA on wave 6's gate-0
  // tile, seeded with bp (att_b at col 100)
  if (w == 6) {
    float bpv6 = bp[96 + lr];
    f32x4 zL = {bpv6, bpv6, bpv6, bpv6};
    #pragma unroll
    for (int kf = 0; kf < 4; ++kf) {
      f16x8 a = *(const f16x8*)(&hS[p][lr][kf * 32 + lq * 8]);
      zL = __builtin_amdgcn_mfma_f32_16x16x32_f16(a, wb[0][kf], zL, 0, 0, 0);
    }
    if (lr == 4) {
      #pragma unroll
      for (int r = 0; r < 4; ++r) logitS[T_STEPS - 1][lq * 4 + r] = zL[r];
    }
  }
  // tail step 38 runnable now (logit[38] visible since last loop barrier)
  if (tail_lane) TAIL_STEP(T_STEPS - 2);
  __syncthreads();
  if (tail_lane) TAIL_STEP(T_STEPS - 1);
  __syncthreads();

  // coalesced output store: 640 floats per output
  if (tid < 160) {
    f32x4 va = ((const f32x4*)&accS[0][0][0])[tid];
    f32x4 vt = ((const f32x4*)&accS[1][0][0])[tid];
    *(f32x4*)(out + (size_t)b0g * T_STEPS + tid * 4) = va;
    *(f32x4*)(out + (size_t)B_TOT * T_STEPS + (size_t)b0g * T_STEPS + tid * 4) = vt;
  }
}

extern "C" void kernel_launch(void* const* d_in, const int* in_sizes, int n_in,
                              void* d_out, int out_size, void* d_ws, size_t ws_size,
                              hipStream_t stream) {
  const float* z_att      = (const float*)d_in[0];
  const float* idm_params = (const float*)d_in[2];
  const float* idm_s      = (const float*)d_in[3];
  const float* sdv_acts   = (const float*)d_in[4];
  const float* linear_W   = (const float*)d_in[5];
  const float* linear_b   = (const float*)d_in[6];
  const float* lstm_Wx    = (const float*)d_in[7];
  const float* lstm_Wh    = (const float*)d_in[8];
  const float* lstm_b     = (const float*)d_in[9];
  const float* att_W      = (const float*)d_in[10];
  const float* att_b      = (const float*)d_in[11];
  const float* noise_f    = (const float*)d_in[12];
  const float* noise_m    = (const float*)d_in[13];
  float* out = (float*)d_out;

  f16*   whb = (f16*)d_ws;
  f16*   wxb = (f16*)((char*)d_ws + 131072);
  float* bp  = (float*)((char*)d_ws + 262144);

  idm_prep<<<256, 256, 0, stream>>>(lstm_Wx, lstm_Wh, lstm_b, att_W, att_b,
                                    whb, wxb, bp);
  idm_main<<<B_TOT / NB, 448, 0, stream>>>(z_att, linear_W, linear_b, sdv_acts,
                                           whb, wxb, bp,
                                           idm_params, idm_s,
                                           noise_f, noise_m, out);
}

// Round 10
// 176.025 us; speedup vs baseline: 1.0182x; 1.0182x over previous
//
#include <hip/hip_runtime.h>
#include <math.h>

// IDMForwardSim R15: R13 (best: 94.4us steady) + half-step anti-phase stagger.
// R14's setprio test was confounded (sched-region fences added ~3.5MB spill
// traffic, WRITE_SIZE 4352->7936KB, dur +5us) — reverted. Phase theory stands:
// pipes sum to ~57% busy, ideal overlapped wall ~2.3Kcy/step vs 5.66Kcy
// measured; the two co-resident blocks run their MFMA/trans phases in lockstep
// (identical step time + barrier makes in-phase a stable fixed point).
// Fix: blocks with bit8 set (co-resident pair on a CU differs by 256 under
// 256-CU round-robin dispatch) sleep ~2816cy (s_sleep(44)) once before the
// t-loop -> pair runs half-step anti-phase; one block's MFMA/LDS phase fills
// the other's trans phase. No in-loop overhead, no register pressure change.
// Otherwise R13: NB=16, 448 thr, 2 blocks/CU; tail-in-loop lag-2 wave 0 with
// 3-reg state (params in LDS pS, att_b folded into bp[100]); exp2 constants
// pre-folded into weights; fused-reciprocal gates.

#define B_TOT 8192
#define T_STEPS 40
#define NB 16

typedef _Float16 f16;
typedef f16 f16x8 __attribute__((ext_vector_type(8)));
typedef float f32x4 __attribute__((ext_vector_type(4)));

__device__ __forceinline__ float rcpf(float x) { return __builtin_amdgcn_rcpf(x); }
__device__ __forceinline__ float ex2(float x)  { return __builtin_amdgcn_exp2f(x); }
__device__ __forceinline__ float sigf(float x)  { return rcpf(1.f + ex2(-1.44269504f * x)); }

// ws layout (bytes): whb f16[65536] @0 | wxb f16[65536] @131072 | bp f32[512] @262144

__global__ __launch_bounds__(256) void idm_prep(
    const float* __restrict__ Wx, const float* __restrict__ Wh,
    const float* __restrict__ bvec, const float* __restrict__ attw,
    const float* __restrict__ attB,
    f16* __restrict__ whb, f16* __restrict__ wxb,
    float* __restrict__ bp)
{
  int i = blockIdx.x * 256 + threadIdx.x;  // 0..65535, i = k*512 + n (coalesced reads)
  int k = i >> 9, n = i & 511;
  int g = n >> 7, j128 = n & 127;
  // pre-scale: sigmoid gates (zi,zf,zo) by log2(e), tanh gate (zg) by 2*log2(e)
  float sc = (g == 2) ? 2.88539008f : 1.44269504f;
  float vh = 0.f, vx = 0.f;
  if (j128 < 100) {
    int col = g * 100 + j128;
    if (k < 100)      { vh = Wh[k * 400 + col] * sc; vx = Wx[k * 400 + col] * sc; }
    else if (k < 102) { vh = Wx[k * 400 + col] * sc; }  // sdv rows folded into Wh-pad
  } else if (n == 100 && k < 100) {
    vh = attw[k];  // logit column stays UNSCALED (z[n=100] = h . att_W)
  }
  // dest B-frag index: tile=n>>4, kf=k>>5, l=((k>>3)&3)*16+(n&15), j=k&7
  int idx = (((n >> 4) * 4 + (k >> 5)) * 64 + (((k >> 3) & 3) * 16 + (n & 15))) * 8 + (k & 7);
  whb[idx] = (f16)vh;
  wxb[idx] = (f16)vx;
  if (i < 512) {
    int gg = i >> 7, jj = i & 127;
    float scb = (gg == 2) ? 2.88539008f : 1.44269504f;
    // bp[100] carries att_b (logit column bias); other pad cols stay 0
    bp[i] = (jj < 100) ? bvec[gg * 100 + jj] * scb
                       : ((i == 100) ? attB[0] : 0.f);
  }
}

#define MM(z, a, g, kf) z = __builtin_amdgcn_mfma_f32_16x16x32_f16(a, wb[g][kf], z, 0, 0, 0)

// tail step (wave 0, lanes 0..15). Per-batch params read from LDS pS each
// step; only ego_v/ego_x/actT live across the t-loop.
#define TAIL_STEP(tt) {                                                        \
    int tt_ = (tt);                                                            \
    float inv_dv = pS[0][l], des_tg = pS[1][l], min_jx = pS[2][l];             \
    float max_a = pS[3][l], inv2s = pS[4][l];                                  \
    float2 s01 = *(const float2*)&sS[l][tt_][0];                               \
    float2 s23 = *(const float2*)&sS[l][tt_][2];                               \
    float2 s45 = *(const float2*)&sS[l][tt_][4];                               \
    float nf = nS[0][tt_][l], nm = nS[1][tt_][l];                              \
    float lg = logitS[tt_][l];                                                 \
    ego_v += actT * 0.1f;                                                      \
    ego_x += ego_v * 0.1f + actT * 0.005f;                                     \
    float dxf = fminf(fmaxf(s23.x - ego_x, 0.5f), 1000.f);                     \
    float dgf = min_jx + fmaxf(0.f, des_tg * ego_v + ego_v * (ego_v - s01.x) * inv2s); \
    float rr = ego_v * inv_dv; float rr2 = rr * rr;                            \
    float qf = dgf * rcpf(dxf);                                                \
    float af_ = fminf(fmaxf(max_a * (1.f - rr2 * rr2 - qf * qf), -3.f), 3.f);  \
    float dxm = fminf(fmaxf(s23.y - ego_x, 0.5f), 1000.f);                     \
    float dgm = min_jx + fmaxf(0.f, des_tg * ego_v + ego_v * (ego_v - s01.y) * inv2s); \
    float qm = dgm * rcpf(dxm);                                                \
    float am_ = fminf(fmaxf(max_a * (1.f - rr2 * rr2 - qm * qm), -3.f), 3.f);  \
    float ef2 = s45.x * af_ + (1.f - s45.x) * nf;                              \
    float em2 = s45.y * am_ + (1.f - s45.y) * nm;                              \
    float att = sigf(5.f * lg);                                                \
    actT = (1.f - att) * ef2 + att * em2;                                      \
    accS[0][l][tt_] = actT;                                                    \
    accS[1][l][tt_] = att;                                                     \
  }

__global__ __launch_bounds__(448, 4) void idm_main(
    const float* __restrict__ z_att,
    const float* __restrict__ linear_W,
    const float* __restrict__ linear_b,
    const float* __restrict__ sdv_acts,
    const f16* __restrict__ whb, const f16* __restrict__ wxb,
    const float* __restrict__ bp,
    const float* __restrict__ idm_params,
    const float* __restrict__ idm_s,
    const float* __restrict__ noise_f,
    const float* __restrict__ noise_m,
    float* __restrict__ out)
{
  __shared__ f16   hS[2][16][136];       // [buf][batch][k] 0..99 h, 100..101 sdv, pad 0
  __shared__ f16   sdvS[T_STEPS][16][2];
  __shared__ float logitS[T_STEPS][16];
  __shared__ float sS[16][T_STEPS][6];   // idm_s fields 1,2,4,5,6,7
  __shared__ float nS[2][T_STEPS][16];   // noise_f / noise_m
  __shared__ float accS[2][16][T_STEPS]; // act, att
  __shared__ float pS[5][16];            // inv_dv, des_tg, min_jx, max_a, inv2s

  const int tid = threadIdx.x;
  const int w  = tid >> 6;   // 0..6 j-tile
  const int l  = tid & 63;
  const int lr = l & 15;
  const int lq = l >> 4;
  const int b0g = blockIdx.x * NB;
  const int jcol = 16 * w + lr;
  const bool tail_lane = (tid < NB);  // wave 0, lanes 0..15

  // zero hS (pad rows must stay exact 0)
  for (int idx = tid; idx < 2176; idx += 448) ((unsigned*)hS)[idx] = 0u;
  // coalesced staging: sdv (1280 f), idm_s fields (5120 f), noise (1280 f)
  for (int idx = tid; idx < 1280; idx += 448) {
    float v = sdv_acts[(size_t)b0g * 80 + idx];
    int b = idx / 80, r = idx - b * 80;
    sdvS[r >> 1][b][r & 1] = (f16)v;
  }
  for (int idx = tid; idx < 5120; idx += 448) {
    int f = idx & 7;
    if (f != 0 && f != 3) {
      int b = idx / 320, rem = idx - b * 320, t = rem >> 3;
      sS[b][t][(f < 3) ? f - 1 : f - 2] = idm_s[(size_t)b0g * 320 + idx];
    }
  }
  for (int idx = tid; idx < 1280; idx += 448) {
    int which = idx >= 640 ? 1 : 0;
    int r = idx - which * 640;
    int t = r >> 4, i = r & 15;
    nS[which][t][i] = which ? noise_m[(size_t)t * B_TOT + b0g + i]
                            : noise_f[(size_t)t * B_TOT + b0g + i];
  }
  // params: 80 consecutive floats, coalesced; pS[j][b] = idm_params[(b0g+b)*5+j]
  if (tid < 80) pS[tid % 5][tid / 5] = idm_params[(size_t)b0g * 5 + tid];
  __syncthreads();

  // in-place transform: pS[0] -> 1/des_v, pS[4] -> 0.5/sqrt(max_a*min_a)
  if (tid < 16) {
    pS[0][tid] = rcpf(pS[0][tid]);
    pS[4][tid] = 0.5f / sqrtf(pS[3][tid] * pS[4][tid]);
  }

  // h0 = att_proj into hS[0]
  if (tid >= 64 && tid < 320) {
    int s2 = tid - 64;
    int b = s2 >> 4, oct = s2 & 15;
    float za[10];
    #pragma unroll
    for (int t2 = 0; t2 < 10; ++t2) za[t2] = z_att[(b0g + b) * 10 + t2];
    #pragma unroll
    for (int jj = 0; jj < 8; ++jj) {
      int j = oct * 8 + jj;
      if (j < 100) {
        float acc = linear_b[j];
        #pragma unroll
        for (int t2 = 0; t2 < 10; ++t2) acc = fmaf(za[t2], linear_W[t2 * 100 + j], acc);
        hS[0][b][j] = (f16)acc;
      }
    }
  }
  if (tid < 32) hS[0][tid >> 1][100 + (tid & 1)] = sdvS[0][tid >> 1][tid & 1];
  __syncthreads();

  // Wx frags -> cx, then Wh frags (loop-invariant in regs)
  f16x8 wb[4][4];
  #pragma unroll
  for (int g = 0; g < 4; ++g) {
    int tile = w + 8 * g;
    #pragma unroll
    for (int kf = 0; kf < 4; ++kf)
      wb[g][kf] = *(const f16x8*)(wxb + ((size_t)(tile * 4 + kf) * 64 + l) * 8);
  }
  f32x4 cx[4];
  #pragma unroll
  for (int g = 0; g < 4; ++g) {
    float bpv = bp[(w + 8 * g) * 16 + lr];
    f32x4 c = {bpv, bpv, bpv, bpv};
    cx[g] = c;
  }
  #pragma unroll
  for (int kf = 0; kf < 4; ++kf) {
    f16x8 a = *(const f16x8*)(&hS[0][lr][kf * 32 + lq * 8]);
    #pragma unroll
    for (int g = 0; g < 4; ++g)
      cx[g] = __builtin_amdgcn_mfma_f32_16x16x32_f16(a, wb[g][kf], cx[g], 0, 0, 0);
  }
  #pragma unroll
  for (int g = 0; g < 4; ++g) {
    int tile = w + 8 * g;
    #pragma unroll
    for (int kf = 0; kf < 4; ++kf)
      wb[g][kf] = *(const f16x8*)(whb + ((size_t)(tile * 4 + kf) * 64 + l) * 8);
  }

  float cst[4];
  #pragma unroll
  for (int r = 0; r < 4; ++r) cst[r] = (float)hS[0][lq * 4 + r][jcol];

  // tail recurrent state: the ONLY tail registers live across the t-loop
  float ego_v = 0.f, ego_x = 0.f, actT = 0.f;
  if (tail_lane) {
    ego_v = idm_s[(size_t)(b0g + l) * 320 + 0];
    ego_x = idm_s[(size_t)(b0g + l) * 320 + 3];
  }

  // Anti-phase stagger: co-resident block pair on a CU differs by 256 in
  // blockIdx (512 blocks round-robin over 256 CUs), so bit8 selects exactly
  // one of each pair. Half a step is ~2830 cy; s_sleep(44) ~= 44*64 = 2816 cy.
  // Shifts this block's MFMA/trans phases against its sibling's for all 40
  // steps; costs nothing inside the loop.
  if ((blockIdx.x >> 8) & 1) __builtin_amdgcn_s_sleep(44);

  int p = 0;
  for (int t = 0; t < T_STEPS; ++t) {
    // A-frags for [h^{(t)}, sdv_t]
    f16x8 a0 = *(const f16x8*)(&hS[p][lr][0  + lq * 8]);
    f16x8 a1 = *(const f16x8*)(&hS[p][lr][32 + lq * 8]);
    f16x8 a2 = *(const f16x8*)(&hS[p][lr][64 + lq * 8]);
    f16x8 a3 = *(const f16x8*)(&hS[p][lr][96 + lq * 8]);
    f32x4 z0 = cx[0], z1 = cx[1], z2 = cx[2], z3 = cx[3];
    MM(z0,a0,0,0); MM(z1,a0,1,0); MM(z2,a0,2,0); MM(z3,a0,3,0);
    MM(z0,a1,0,1); MM(z1,a1,1,1); MM(z2,a1,2,1); MM(z3,a1,3,1);
    MM(z0,a2,0,2); MM(z1,a2,1,2); MM(z2,a2,2,2); MM(z3,a2,3,2);
    MM(z0,a3,0,3); MM(z1,a3,1,3); MM(z2,a3,2,3); MM(z3,a3,3,3);

    // logit for output t-1: z col n=100 (tile 6 = wave 6 g=0, lane lr==4);
    // includes att_b via bp[100] folded into cx
    if (w == 6 && t > 0 && lr == 4) {
      #pragma unroll
      for (int r = 0; r < 4; ++r) logitS[t - 1][lq * 4 + r] = z0[r];
    }

    // gates with fused reciprocals: si*tg = (e2-1)/((1+e0)(1+e2)),
    // so*tanh(cc) = (d-1)/((1+e3)(1+d)); e2,d clamped so overflow -> 0, no NaN.
    #pragma unroll
    for (int r = 0; r < 4; ++r) {
      float e0 = ex2(-z0[r]);
      float e1 = ex2(-z1[r]);
      float e2 = fminf(ex2(z2[r]), 1e30f);
      float e3 = ex2(-z3[r]);
      float sf  = rcpf(1.f + e1);
      float itg = (e2 - 1.f) * rcpf((1.f + e0) * (1.f + e2));  // si*tg
      float cc  = fmaf(sf, cst[r], itg);
      float d   = fminf(ex2(2.88539008f * cc), 1e30f);
      float hh  = (d - 1.f) * rcpf((1.f + e3) * (1.f + d));    // so*tanh(cc)
      cst[r] = cc;
      if (jcol < 100) hS[p ^ 1][lq * 4 + r][jcol] = (f16)hh;
    }
    if (t + 1 < T_STEPS && tid < 32)
      hS[p ^ 1][tid >> 1][100 + (tid & 1)] = sdvS[t + 1][tid >> 1][tid & 1];
    // wave 0 lanes 0..15: lag-2 tail step (logit[t-2] visible since end of
    // step t-1); independent of this wave's gates, scheduler interleaves
    if (tail_lane && t >= 2) TAIL_STEP(t - 2);
    __syncthreads();  // single barrier per step
    p ^= 1;
  }

  // final logit (t = T-1) from h^{(T)} in hS[p]: 4 MFMA on wave 6's gate-0
  // tile, seeded with bp (att_b at col 100)
  if (w == 6) {
    float bpv6 = bp[96 + lr];
    f32x4 zL = {bpv6, bpv6, bpv6, bpv6};
    #pragma unroll
    for (int kf = 0; kf < 4; ++kf) {
      f16x8 a = *(const f16x8*)(&hS[p][lr][kf * 32 + lq * 8]);
      zL = __builtin_amdgcn_mfma_f32_16x16x32_f16(a, wb[0][kf], zL, 0, 0, 0);
    }
    if (lr == 4) {
      #pragma unroll
      for (int r = 0; r < 4; ++r) logitS[T_STEPS - 1][lq * 4 + r] = zL[r];
    }
  }
  // tail step 38 runnable now (logit[38] visible since last loop barrier)
  if (tail_lane) TAIL_STEP(T_STEPS - 2);
  __syncthreads();
  if (tail_lane) TAIL_STEP(T_STEPS - 1);
  __syncthreads();

  // coalesced output store: 640 floats per output
  if (tid < 160) {
    f32x4 va = ((const f32x4*)&accS[0][0][0])[tid];
    f32x4 vt = ((const f32x4*)&accS[1][0][0])[tid];
    *(f32x4*)(out + (size_t)b0g * T_STEPS + tid * 4) = va;
    *(f32x4*)(out + (size_t)B_TOT * T_STEPS + (size_t)b0g * T_STEPS + tid * 4) = vt;
  }
}

extern "C" void kernel_launch(void* const* d_in, const int* in_sizes, int n_in,
                              void* d_out, int out_size, void* d_ws, size_t ws_size,
                              hipStream_t stream) {
  const float* z_att      = (const float*)d_in[0];
  const float* idm_params = (const float*)d_in[2];
  const float* idm_s      = (const float*)d_in[3];
  const float* sdv_acts   = (const float*)d_in[4];
  const float* linear_W   = (const float*)d_in[5];
  const float* linear_b   = (const float*)d_in[6];
  const float* lstm_Wx    = (const float*)d_in[7];
  const float* lstm_Wh    = (const float*)d_in[8];
  const float* lstm_b     = (const float*)d_in[9];
  const float* att_W      = (const float*)d_in[10];
  const float* att_b      = (const float*)d_in[11];
  const float* noise_f    = (const float*)d_in[12];
  const float* noise_m    = (const float*)d_in[13];
  float* out = (float*)d_out;

  f16*   whb = (f16*)d_ws;
  f16*   wxb = (f16*)((char*)d_ws + 131072);
  float* bp  = (float*)((char*)d_ws + 262144);

  idm_prep<<<256, 256, 0, stream>>>(lstm_Wx, lstm_Wh, lstm_b, att_W, att_b,
                                    whb, wxb, bp);
  idm_main<<<B_TOT / NB, 448, 0, stream>>>(z_att, linear_W, linear_b, sdv_acts,
                                           whb, wxb, bp,
                                           idm_params, idm_s,
                                           noise_f, noise_m, out);
}